// Round 1
// baseline (216.673 us; speedup 1.0000x reference)
//
#include <hip/hip_runtime.h>
#include <hip/hip_bf16.h>

// PAM module: B=4, N=4096 (64x64), C=64.
// out[b,n,c] = gamma * sum_m softmax_row(q@k^T)[m,n] * v[m,c] + x[b,n,c]
//
// Strategy: bf16 MFMA (16x16x32), energy recomputed (never materialized).
//  K0: W -> W^T bf16
//  K1: q,k,v projections (MFMA); q,k row-major bf16; v transposed [c][n] bf16
//  K2: rowsum s[m] = sum_n exp(e[m,n]); rinv = 1/s  (no max-sub: |e| << 88)
//  K3: out[n,c] = sum_m exp(e[m,n])*rinv[m] * v[m,c], epilogue gamma*acc + x

typedef __attribute__((ext_vector_type(8))) short short8;   // 8 bf16 = 16B (MFMA A/B frag)
typedef __attribute__((ext_vector_type(4))) float f32x4;
typedef __attribute__((ext_vector_type(4))) unsigned int u32x4;
typedef __attribute__((ext_vector_type(2))) unsigned int u32x2;

#define DEV static __device__ __forceinline__

DEV unsigned short f2bf(float f) {
    __hip_bfloat16 h = __float2bfloat16(f);
    return __builtin_bit_cast(unsigned short, h);
}
DEV unsigned int pack2(float lo, float hi) {
    return (unsigned int)f2bf(lo) | ((unsigned int)f2bf(hi) << 16);
}
DEV f32x4 MFMA(short8 a, short8 b, f32x4 c) {
    return __builtin_amdgcn_mfma_f32_16x16x32_bf16(a, b, c, 0, 0, 0);
}

// ws layout (bytes)
#define OFF_Q    0u          // [16384][64] bf16 = 2 MB
#define OFF_K    2097152u    // [16384][64] bf16 = 2 MB
#define OFF_VT   4194304u    // [4][64][4096] bf16 = 2 MB   (v transposed per batch)
#define OFF_WT   6291456u    // [3][64][64] bf16 = 24 KB    (Wq^T, Wk^T, Wv^T)
#define OFF_RINV 6316032u    // [4][4096] f32 = 64 KB

// ---------------- K0: weight transpose to bf16 ----------------
__global__ __launch_bounds__(256) void k0_wt(const float* __restrict__ Wq,
                                             const float* __restrict__ Wk,
                                             const float* __restrict__ Wv,
                                             unsigned short* __restrict__ wt) {
    int e = blockIdx.x * 256 + threadIdx.x;
    if (e >= 3 * 4096) return;
    int w3 = e >> 12, rem = e & 4095, f = rem >> 6, c = rem & 63;
    const float* W = (w3 == 0) ? Wq : (w3 == 1) ? Wk : Wv;
    wt[e] = f2bf(W[c * 64 + f]);   // wt[w3][f][c] = W[c][f]
}

// ---------------- K1: projections ----------------
// grid 256: block handles 64 global rows (= b*4096+n). 4 waves x 16 rows.
__global__ __launch_bounds__(256) void k1_proj(const float* __restrict__ x,
                                               const unsigned short* __restrict__ wt,
                                               const float* __restrict__ bq,
                                               const float* __restrict__ bk,
                                               const float* __restrict__ bv,
                                               unsigned short* __restrict__ qg,
                                               unsigned short* __restrict__ kg,
                                               unsigned short* __restrict__ vtg) {
    __shared__ __align__(16) char XT[8192];     // [64 rows][128B], swizzled
    __shared__ __align__(16) char WT[24576];    // 3 x [64 f][128B c], swizzled
    __shared__ __align__(16) char VTILE[9216];  // [64 f][72 m] bf16 (pad vs bank conflicts)
    int t = threadIdx.x, blk = blockIdx.x;

    { // stage x tile (fp32 -> bf16, swizzled)
        int m = t >> 2, q4 = t & 3;
        const f32x4* xs = (const f32x4*)(x + (size_t)(blk * 64 + m) * 64 + q4 * 16);
        f32x4 fa = xs[0], fbv = xs[1], fc = xs[2], fd = xs[3];
        u32x4 u0 = { pack2(fa[0],fa[1]), pack2(fa[2],fa[3]), pack2(fbv[0],fbv[1]), pack2(fbv[2],fbv[3]) };
        u32x4 u1 = { pack2(fc[0],fc[1]), pack2(fc[2],fc[3]), pack2(fd[0],fd[1]), pack2(fd[2],fd[3]) };
        int sw = (m & 7) << 4;
        *(u32x4*)(XT + m * 128 + ((q4 * 32) ^ sw)) = u0;
        *(u32x4*)(XT + m * 128 + ((q4 * 32 + 16) ^ sw)) = u1;
    }
    // stage the three W^T tiles
    for (int w3 = 0; w3 < 3; ++w3) {
        int f = t >> 2, q4 = t & 3;
        const u32x4* s = (const u32x4*)(wt + w3 * 4096 + f * 64 + q4 * 16);
        u32x4 u0 = s[0], u1 = s[1];
        int sw = (f & 7) << 4;
        *(u32x4*)(WT + w3 * 8192 + f * 128 + ((q4 * 32) ^ sw)) = u0;
        *(u32x4*)(WT + w3 * 8192 + f * 128 + ((q4 * 32 + 16) ^ sw)) = u1;
    }
    __syncthreads();

    int lane = t & 63, wid = t >> 6, g = lane >> 4, ln = lane & 15;
    int arow = wid * 16 + ln;
    short8 a0 = *(const short8*)(XT + arow * 128 + ((16 * g) ^ ((arow & 7) << 4)));
    short8 a1 = *(const short8*)(XT + arow * 128 + ((64 + 16 * g) ^ ((arow & 7) << 4)));

    for (int w3 = 0; w3 < 3; ++w3) {
        const char* wtile = WT + w3 * 8192;
        const float* bias = (w3 == 0) ? bq : (w3 == 1) ? bk : bv;
        #pragma unroll
        for (int fb = 0; fb < 4; ++fb) {
            int frow = fb * 16 + ln;
            short8 b0 = *(const short8*)(wtile + frow * 128 + ((16 * g) ^ ((frow & 7) << 4)));
            short8 b1 = *(const short8*)(wtile + frow * 128 + ((64 + 16 * g) ^ ((frow & 7) << 4)));
            f32x4 acc = {0.f, 0.f, 0.f, 0.f};
            acc = MFMA(a0, b0, acc);
            acc = MFMA(a1, b1, acc);
            float bval = bias[frow];
            if (w3 < 2) {
                unsigned short* dst = (w3 == 0) ? qg : kg;
                int gr = blk * 64 + wid * 16 + 4 * g;
                #pragma unroll
                for (int r = 0; r < 4; ++r)
                    dst[(size_t)(gr + r) * 64 + frow] = f2bf(acc[r] + bval);
            } else {
                unsigned short* vt = (unsigned short*)VTILE;
                int mloc = wid * 16 + 4 * g;
                #pragma unroll
                for (int r = 0; r < 4; ++r)
                    vt[frow * 72 + mloc + r] = f2bf(acc[r] + bval);
            }
        }
    }
    __syncthreads();
    { // write v^T tile out coalesced: vtg[b][c][n]
        int f = t >> 2, mq = t & 3;
        u32x4 u0 = *(const u32x4*)(VTILE + f * 144 + mq * 32);
        u32x4 u1 = *(const u32x4*)(VTILE + f * 144 + mq * 32 + 16);
        int b = blk >> 6, n0 = (blk & 63) * 64;
        unsigned short* dst = vtg + (size_t)b * 262144 + f * 4096 + n0 + mq * 16;
        *(u32x4*)(dst) = u0;
        *(u32x4*)(dst + 8) = u1;
    }
}

// ---------------- K2: row sums -> rinv ----------------
// grid 256: block = (b, m-block of 64). Wave owns 16 m rows (A-frags in regs),
// streams k tiles (64 n per iter) through swizzled LDS with reg prefetch.
__global__ __launch_bounds__(256) void k2_rowsum(const unsigned short* __restrict__ qg,
                                                 const unsigned short* __restrict__ kg,
                                                 float* __restrict__ rinv) {
    __shared__ __align__(16) char QT[8192];
    __shared__ __align__(16) char KT[8192];
    int t = threadIdx.x, blk = blockIdx.x;
    int b = blk >> 6, m0 = (blk & 63) * 64;
    int row = t >> 2, q4 = t & 3;
    int sw = (row & 7) << 4;

    { // stage own q tile
        const u32x4* s = (const u32x4*)(qg + (size_t)(b * 4096 + m0 + row) * 64 + q4 * 16);
        u32x4 u0 = s[0], u1 = s[1];
        *(u32x4*)(QT + row * 128 + ((q4 * 32) ^ sw)) = u0;
        *(u32x4*)(QT + row * 128 + ((q4 * 32 + 16) ^ sw)) = u1;
    }
    // prefetch k chunk 0
    u32x4 pf0, pf1;
    {
        const u32x4* ks = (const u32x4*)(kg + (size_t)(b * 4096 + row) * 64 + q4 * 16);
        pf0 = ks[0]; pf1 = ks[1];
    }
    __syncthreads();

    int lane = t & 63, wid = t >> 6, g = lane >> 4, ln = lane & 15;
    int arow = wid * 16 + ln;
    short8 a0 = *(const short8*)(QT + arow * 128 + ((16 * g) ^ ((arow & 7) << 4)));
    short8 a1 = *(const short8*)(QT + arow * 128 + ((64 + 16 * g) ^ ((arow & 7) << 4)));

    float acc0 = 0.f, acc1 = 0.f, acc2 = 0.f, acc3 = 0.f;
    for (int nc = 0; nc < 64; ++nc) {
        *(u32x4*)(KT + row * 128 + ((q4 * 32) ^ sw)) = pf0;
        *(u32x4*)(KT + row * 128 + ((q4 * 32 + 16) ^ sw)) = pf1;
        __syncthreads();
        if (nc < 63) {
            const u32x4* ks = (const u32x4*)(kg + (size_t)(b * 4096 + (nc + 1) * 64 + row) * 64 + q4 * 16);
            pf0 = ks[0]; pf1 = ks[1];
        }
        #pragma unroll
        for (int j = 0; j < 4; ++j) {
            int brow = j * 16 + ln;
            short8 b0 = *(const short8*)(KT + brow * 128 + ((16 * g) ^ ((brow & 7) << 4)));
            short8 b1 = *(const short8*)(KT + brow * 128 + ((64 + 16 * g) ^ ((brow & 7) << 4)));
            f32x4 e = {0.f, 0.f, 0.f, 0.f};
            e = MFMA(a0, b0, e);
            e = MFMA(a1, b1, e);
            acc0 += __expf(e[0]); acc1 += __expf(e[1]);
            acc2 += __expf(e[2]); acc3 += __expf(e[3]);
        }
        __syncthreads();
    }
    // reduce across the 16 lanes of each group (cols of the tile)
    #pragma unroll
    for (int msk = 1; msk < 16; msk <<= 1) {
        acc0 += __shfl_xor(acc0, msk);
        acc1 += __shfl_xor(acc1, msk);
        acc2 += __shfl_xor(acc2, msk);
        acc3 += __shfl_xor(acc3, msk);
    }
    if (ln == 0) {
        int base = b * 4096 + m0 + wid * 16 + 4 * g;
        rinv[base + 0] = 1.0f / acc0;
        rinv[base + 1] = 1.0f / acc1;
        rinv[base + 2] = 1.0f / acc2;
        rinv[base + 3] = 1.0f / acc3;
    }
}

// ---------------- K3: out = P^T * V, epilogue gamma*acc + x ----------------
// grid 256: block = (b, n-block of 64). Wave owns 16 n (k B-frags in regs).
// Streams q[32 m][64c] + vT[64c][32 m] per iter; p transposed via per-wave LDS.
__global__ __launch_bounds__(256) void k3_out(const unsigned short* __restrict__ qg,
                                              const unsigned short* __restrict__ kg,
                                              const unsigned short* __restrict__ vtg,
                                              const float* __restrict__ rinv,
                                              const float* __restrict__ x,
                                              const float* __restrict__ gamma,
                                              float* __restrict__ outp) {
    __shared__ __align__(16) char KT[8192];   // [64 n][128B c] swz128
    __shared__ __align__(16) char QT[4096];   // [32 m][128B c] swz128
    __shared__ __align__(16) char VT[4096];   // [64 c][64B m]  swz64
    __shared__ __align__(16) char PL[4096];   // 4 waves x [16 n][64B m] swz64
    int t = threadIdx.x, blk = blockIdx.x;
    int b = blk >> 6, n0 = (blk & 63) * 64;

    { // stage k tile for this n-block
        int row = t >> 2, q4 = t & 3;
        const u32x4* s = (const u32x4*)(kg + (size_t)(b * 4096 + n0 + row) * 64 + q4 * 16);
        u32x4 u0 = s[0], u1 = s[1];
        int sw = (row & 7) << 4;
        *(u32x4*)(KT + row * 128 + ((q4 * 32) ^ sw)) = u0;
        *(u32x4*)(KT + row * 128 + ((q4 * 32 + 16) ^ sw)) = u1;
    }
    // prefetch q/v chunk 0
    int qm = t >> 3, qoct = t & 7;   // qTile row, 16B block
    int vc = t >> 2, vj = t & 3;     // vTile row (c), 16B block
    u32x4 qpf = *(const u32x4*)(qg + (size_t)(b * 4096 + qm) * 64 + qoct * 8);
    u32x4 vpf = *(const u32x4*)(vtg + (size_t)b * 262144 + vc * 4096 + vj * 8);
    __syncthreads();

    int lane = t & 63, wid = t >> 6, g = lane >> 4, ln = lane & 15;
    int krow = wid * 16 + ln;
    short8 kb0 = *(const short8*)(KT + krow * 128 + ((16 * g) ^ ((krow & 7) << 4)));
    short8 kb1 = *(const short8*)(KT + krow * 128 + ((64 + 16 * g) ^ ((krow & 7) << 4)));

    f32x4 z = {0.f, 0.f, 0.f, 0.f};
    f32x4 oacc[4] = {z, z, z, z};
    char* pbase = PL + wid * 1024;
    int psw = ((ln >> 1) & 3) << 4;

    for (int mc = 0; mc < 128; ++mc) {
        { // write staged q/v chunk mc
            int sw = (qm & 7) << 4;
            *(u32x4*)(QT + qm * 128 + ((qoct * 16) ^ sw)) = qpf;
            int sw2 = ((vc >> 1) & 3) << 4;
            *(u32x4*)(VT + vc * 64 + ((vj * 16) ^ sw2)) = vpf;
        }
        __syncthreads();
        if (mc < 127) { // prefetch chunk mc+1 (latency hides under compute)
            int m1 = (mc + 1) * 32;
            qpf = *(const u32x4*)(qg + (size_t)(b * 4096 + m1 + qm) * 64 + qoct * 8);
            vpf = *(const u32x4*)(vtg + (size_t)b * 262144 + vc * 4096 + m1 + vj * 8);
        }
        const float* rp = rinv + b * 4096 + mc * 32;
        #pragma unroll
        for (int s = 0; s < 2; ++s) {
            int qrow = 16 * s + ln;
            int qsw = (qrow & 7) << 4;
            short8 as0 = *(const short8*)(QT + qrow * 128 + ((16 * g) ^ qsw));
            short8 as1 = *(const short8*)(QT + qrow * 128 + ((64 + 16 * g) ^ qsw));
            f32x4 e = {0.f, 0.f, 0.f, 0.f};
            e = MFMA(as0, kb0, e);   // e[m'=4g+r][n=ln], m = mc*32 + 16s + m'
            e = MFMA(as1, kb1, e);
            f32x4 rv = *(const f32x4*)(rp + 16 * s + 4 * g);
            float p0 = __expf(e[0]) * rv[0];
            float p1 = __expf(e[1]) * rv[1];
            float p2 = __expf(e[2]) * rv[2];
            float p3 = __expf(e[3]) * rv[3];
            u32x2 pu = { pack2(p0, p1), pack2(p2, p3) };
            *(u32x2*)(pbase + ln * 64 + ((32 * s + 8 * g) ^ psw)) = pu;
        }
        // PV: A-frag = p[n=ln][m-chunk], B-frag = vT[c][m-chunk]
        short8 pa = *(const short8*)(pbase + ln * 64 + ((16 * g) ^ psw));
        #pragma unroll
        for (int fb = 0; fb < 4; ++fb) {
            int crow = fb * 16 + ln;
            short8 vb = *(const short8*)(VT + crow * 64 + ((16 * g) ^ (((crow >> 1) & 3) << 4)));
            oacc[fb] = MFMA(pa, vb, oacc[fb]);
        }
        __syncthreads();
    }

    float gm = gamma[0];
    int nrow = b * 4096 + n0 + wid * 16 + 4 * g;
    #pragma unroll
    for (int fb = 0; fb < 4; ++fb) {
        #pragma unroll
        for (int r = 0; r < 4; ++r) {
            int idx = (nrow + r) * 64 + fb * 16 + ln;
            outp[idx] = gm * oacc[fb][r] + x[idx];
        }
    }
}

extern "C" void kernel_launch(void* const* d_in, const int* in_sizes, int n_in,
                              void* d_out, int out_size, void* d_ws, size_t ws_size,
                              hipStream_t stream) {
    const float* x  = (const float*)d_in[0];
    const float* Wq = (const float*)d_in[1];
    const float* bq = (const float*)d_in[2];
    const float* Wk = (const float*)d_in[3];
    const float* bk = (const float*)d_in[4];
    const float* Wv = (const float*)d_in[5];
    const float* bv = (const float*)d_in[6];
    const float* gm = (const float*)d_in[7];
    char* ws = (char*)d_ws;
    float* outp = (float*)d_out;

    unsigned short* qg  = (unsigned short*)(ws + OFF_Q);
    unsigned short* kg  = (unsigned short*)(ws + OFF_K);
    unsigned short* vtg = (unsigned short*)(ws + OFF_VT);
    unsigned short* wt  = (unsigned short*)(ws + OFF_WT);
    float* rinv         = (float*)(ws + OFF_RINV);

    k0_wt<<<48, 256, 0, stream>>>(Wq, Wk, Wv, wt);
    k1_proj<<<256, 256, 0, stream>>>(x, wt, bq, bk, bv, qg, kg, vtg);
    k2_rowsum<<<256, 256, 0, stream>>>(qg, kg, rinv);
    k3_out<<<256, 256, 0, stream>>>(qg, kg, vtg, rinv, x, gm, outp);
}

// Round 2
// 136.278 us; speedup vs baseline: 1.5899x; 1.5899x over previous
//
#include <hip/hip_runtime.h>
#include <hip/hip_bf16.h>

// PAM module: B=4, N=4096 (64x64), C=64.
// out[b,n,c] = gamma * sum_m softmax_row(q@k^T)[m,n] * v[m,c] + x[b,n,c]
//
// bf16 MFMA (16x16x32), energy recomputed (never materialized).
//  k0z: W -> W^T bf16, zero s-buffer
//  k1 : q,k,v projections (MFMA); q,k row-major bf16; v transposed [c][n] bf16
//  k2 : partial rowsums s[m] += sum_{n in quarter} exp(e[m,n])  (atomic, n-split 4)
//  r2 : rinv = 1/s ; out <- x
//  k3 : out += gamma * sum_{m in quarter} exp(e[m,n])*rinv[m]*v[m,c] (atomic, m-split 4)

typedef __attribute__((ext_vector_type(8))) short short8;   // 8 bf16 = 16B MFMA frag
typedef __attribute__((ext_vector_type(4))) float f32x4;
typedef __attribute__((ext_vector_type(4))) unsigned int u32x4;
typedef __attribute__((ext_vector_type(2))) unsigned int u32x2;

#define DEV static __device__ __forceinline__

DEV unsigned short f2bf(float f) {
    __hip_bfloat16 h = __float2bfloat16(f);
    return __builtin_bit_cast(unsigned short, h);
}
DEV unsigned int pack2(float lo, float hi) {
    return (unsigned int)f2bf(lo) | ((unsigned int)f2bf(hi) << 16);
}
DEV f32x4 MFMA(short8 a, short8 b, f32x4 c) {
    return __builtin_amdgcn_mfma_f32_16x16x32_bf16(a, b, c, 0, 0, 0);
}

// ws layout (bytes)
#define OFF_Q    0u          // [16384][64] bf16 = 2 MB
#define OFF_K    2097152u    // [16384][64] bf16 = 2 MB
#define OFF_VT   4194304u    // [4][64][4096] bf16 = 2 MB
#define OFF_WT   6291456u    // [3][64][64] bf16 = 24 KB
#define OFF_S    6316032u    // [16384] f32 = 64 KB (row sums, atomic)
#define OFF_RINV 6381568u    // [16384] f32 = 64 KB

// ---------------- k0z: weight transpose + zero s ----------------
__global__ __launch_bounds__(256) void k0z(const float* __restrict__ Wq,
                                           const float* __restrict__ Wk,
                                           const float* __restrict__ Wv,
                                           unsigned short* __restrict__ wt,
                                           float* __restrict__ sbuf) {
    int e = blockIdx.x * 256 + threadIdx.x;   // grid 64 -> e in [0,16384)
    sbuf[e] = 0.0f;
    if (e < 3 * 4096) {
        int w3 = e >> 12, rem = e & 4095, f = rem >> 6, c = rem & 63;
        const float* W = (w3 == 0) ? Wq : (w3 == 1) ? Wk : Wv;
        wt[e] = f2bf(W[c * 64 + f]);   // wt[w3][f][c] = W[c][f]
    }
}

// ---------------- k1: projections (unchanged) ----------------
__global__ __launch_bounds__(256) void k1_proj(const float* __restrict__ x,
                                               const unsigned short* __restrict__ wt,
                                               const float* __restrict__ bq,
                                               const float* __restrict__ bk,
                                               const float* __restrict__ bv,
                                               unsigned short* __restrict__ qg,
                                               unsigned short* __restrict__ kg,
                                               unsigned short* __restrict__ vtg) {
    __shared__ __align__(16) char XT[8192];
    __shared__ __align__(16) char WT[24576];
    __shared__ __align__(16) char VTILE[9216];
    int t = threadIdx.x, blk = blockIdx.x;

    {
        int m = t >> 2, q4 = t & 3;
        const f32x4* xs = (const f32x4*)(x + (size_t)(blk * 64 + m) * 64 + q4 * 16);
        f32x4 fa = xs[0], fbv = xs[1], fc = xs[2], fd = xs[3];
        u32x4 u0 = { pack2(fa[0],fa[1]), pack2(fa[2],fa[3]), pack2(fbv[0],fbv[1]), pack2(fbv[2],fbv[3]) };
        u32x4 u1 = { pack2(fc[0],fc[1]), pack2(fc[2],fc[3]), pack2(fd[0],fd[1]), pack2(fd[2],fd[3]) };
        int sw = (m & 7) << 4;
        *(u32x4*)(XT + m * 128 + ((q4 * 32) ^ sw)) = u0;
        *(u32x4*)(XT + m * 128 + ((q4 * 32 + 16) ^ sw)) = u1;
    }
    for (int w3 = 0; w3 < 3; ++w3) {
        int f = t >> 2, q4 = t & 3;
        const u32x4* s = (const u32x4*)(wt + w3 * 4096 + f * 64 + q4 * 16);
        u32x4 u0 = s[0], u1 = s[1];
        int sw = (f & 7) << 4;
        *(u32x4*)(WT + w3 * 8192 + f * 128 + ((q4 * 32) ^ sw)) = u0;
        *(u32x4*)(WT + w3 * 8192 + f * 128 + ((q4 * 32 + 16) ^ sw)) = u1;
    }
    __syncthreads();

    int lane = t & 63, wid = t >> 6, g = lane >> 4, ln = lane & 15;
    int arow = wid * 16 + ln;
    short8 a0 = *(const short8*)(XT + arow * 128 + ((16 * g) ^ ((arow & 7) << 4)));
    short8 a1 = *(const short8*)(XT + arow * 128 + ((64 + 16 * g) ^ ((arow & 7) << 4)));

    for (int w3 = 0; w3 < 3; ++w3) {
        const char* wtile = WT + w3 * 8192;
        const float* bias = (w3 == 0) ? bq : (w3 == 1) ? bk : bv;
        #pragma unroll
        for (int fb = 0; fb < 4; ++fb) {
            int frow = fb * 16 + ln;
            short8 b0 = *(const short8*)(wtile + frow * 128 + ((16 * g) ^ ((frow & 7) << 4)));
            short8 b1 = *(const short8*)(wtile + frow * 128 + ((64 + 16 * g) ^ ((frow & 7) << 4)));
            f32x4 acc = {0.f, 0.f, 0.f, 0.f};
            acc = MFMA(a0, b0, acc);
            acc = MFMA(a1, b1, acc);
            float bval = bias[frow];
            if (w3 < 2) {
                unsigned short* dst = (w3 == 0) ? qg : kg;
                int gr = blk * 64 + wid * 16 + 4 * g;
                #pragma unroll
                for (int r = 0; r < 4; ++r)
                    dst[(size_t)(gr + r) * 64 + frow] = f2bf(acc[r] + bval);
            } else {
                unsigned short* vt = (unsigned short*)VTILE;
                int mloc = wid * 16 + 4 * g;
                #pragma unroll
                for (int r = 0; r < 4; ++r)
                    vt[frow * 72 + mloc + r] = f2bf(acc[r] + bval);
            }
        }
    }
    __syncthreads();
    {
        int f = t >> 2, mq = t & 3;
        u32x4 u0 = *(const u32x4*)(VTILE + f * 144 + mq * 32);
        u32x4 u1 = *(const u32x4*)(VTILE + f * 144 + mq * 32 + 16);
        int b = blk >> 6, n0 = (blk & 63) * 64;
        unsigned short* dst = vtg + (size_t)b * 262144 + f * 4096 + n0 + mq * 16;
        *(u32x4*)(dst) = u0;
        *(u32x4*)(dst + 8) = u1;
    }
}

// ---------------- k2: partial row sums (n-split 4, atomic) ----------------
// grid 1024: blk = b*256 + ns*64 + mb. Block: 64 m rows, streams 16 k-chunks of 64 n.
__global__ __launch_bounds__(256) void k2_rowsum(const unsigned short* __restrict__ qg,
                                                 const unsigned short* __restrict__ kg,
                                                 float* __restrict__ sbuf) {
    __shared__ __align__(16) char QT[8192];
    __shared__ __align__(16) char KT[8192];
    int t = threadIdx.x, blk = blockIdx.x;
    int b = blk >> 8, ns = (blk >> 6) & 3, mb = blk & 63;
    int m0 = mb * 64, nbase = ns * 1024;
    int row = t >> 2, q4 = t & 3;
    int sw = (row & 7) << 4;

    {   // stage own q tile
        const u32x4* s = (const u32x4*)(qg + (size_t)(b * 4096 + m0 + row) * 64 + q4 * 16);
        u32x4 u0 = s[0], u1 = s[1];
        *(u32x4*)(QT + row * 128 + ((q4 * 32) ^ sw)) = u0;
        *(u32x4*)(QT + row * 128 + ((q4 * 32 + 16) ^ sw)) = u1;
    }
    u32x4 pf0, pf1;
    {
        const u32x4* ks = (const u32x4*)(kg + (size_t)(b * 4096 + nbase + row) * 64 + q4 * 16);
        pf0 = ks[0]; pf1 = ks[1];
    }
    __syncthreads();

    int lane = t & 63, wid = t >> 6, g = lane >> 4, ln = lane & 15;
    int arow = wid * 16 + ln;
    short8 a0 = *(const short8*)(QT + arow * 128 + ((16 * g) ^ ((arow & 7) << 4)));
    short8 a1 = *(const short8*)(QT + arow * 128 + ((64 + 16 * g) ^ ((arow & 7) << 4)));

    float acc0 = 0.f, acc1 = 0.f, acc2 = 0.f, acc3 = 0.f;
    for (int nc = 0; nc < 16; ++nc) {
        *(u32x4*)(KT + row * 128 + ((q4 * 32) ^ sw)) = pf0;
        *(u32x4*)(KT + row * 128 + ((q4 * 32 + 16) ^ sw)) = pf1;
        __syncthreads();
        if (nc < 15) {
            const u32x4* ks = (const u32x4*)(kg + (size_t)(b * 4096 + nbase + (nc + 1) * 64 + row) * 64 + q4 * 16);
            pf0 = ks[0]; pf1 = ks[1];
        }
        #pragma unroll
        for (int j = 0; j < 4; ++j) {
            int brow = j * 16 + ln;
            short8 b0 = *(const short8*)(KT + brow * 128 + ((16 * g) ^ ((brow & 7) << 4)));
            short8 b1 = *(const short8*)(KT + brow * 128 + ((64 + 16 * g) ^ ((brow & 7) << 4)));
            f32x4 e = {0.f, 0.f, 0.f, 0.f};
            e = MFMA(a0, b0, e);
            e = MFMA(a1, b1, e);
            acc0 += __expf(e[0]); acc1 += __expf(e[1]);
            acc2 += __expf(e[2]); acc3 += __expf(e[3]);
        }
        __syncthreads();
    }
    #pragma unroll
    for (int msk = 1; msk < 16; msk <<= 1) {
        acc0 += __shfl_xor(acc0, msk);
        acc1 += __shfl_xor(acc1, msk);
        acc2 += __shfl_xor(acc2, msk);
        acc3 += __shfl_xor(acc3, msk);
    }
    if (ln == 0) {
        float* base = sbuf + b * 4096 + m0 + wid * 16 + 4 * g;
        unsafeAtomicAdd(base + 0, acc0);
        unsafeAtomicAdd(base + 1, acc1);
        unsafeAtomicAdd(base + 2, acc2);
        unsafeAtomicAdd(base + 3, acc3);
    }
}

// ---------------- r2: rinv = 1/s ; out <- x ----------------
__global__ __launch_bounds__(256) void r2_init(const float* __restrict__ sbuf,
                                               float* __restrict__ rinv,
                                               const float* __restrict__ x,
                                               float* __restrict__ outp) {
    int tid = blockIdx.x * 256 + threadIdx.x;   // grid 1024 -> [0, 262144)
    if (tid < 16384) rinv[tid] = 1.0f / sbuf[tid];
    f32x4 v = *(const f32x4*)(x + 4 * (size_t)tid);
    *(f32x4*)(outp + 4 * (size_t)tid) = v;
}

// ---------------- k3: out += gamma * P^T V  (m-split 4, atomic) ----------------
// grid 1024: blk = b*256 + ms*64 + nb. Block: 64 n, streams 16 chunks of 64 m.
__global__ __launch_bounds__(256) void k3_out(const unsigned short* __restrict__ qg,
                                              const unsigned short* __restrict__ kg,
                                              const unsigned short* __restrict__ vtg,
                                              const float* __restrict__ rinv,
                                              const float* __restrict__ gamma,
                                              float* __restrict__ outp) {
    __shared__ __align__(16) char KT[8192];   // [64 n][128B c] swz128
    __shared__ __align__(16) char QT[8192];   // [64 m][128B c] swz128
    __shared__ __align__(16) char VT[8192];   // [64 c][128B m] swz128
    __shared__ __align__(16) char PL[8192];   // 4 waves x [16 n][128B m] swz128
    int t = threadIdx.x, blk = blockIdx.x;
    int b = blk >> 8, ms = (blk >> 6) & 3, nb = blk & 63;
    int n0 = nb * 64, mbase = ms * 1024;
    int row = t >> 2, q4 = t & 3;
    int sw = (row & 7) << 4;

    {   // stage k tile for this n-block
        const u32x4* s = (const u32x4*)(kg + (size_t)(b * 4096 + n0 + row) * 64 + q4 * 16);
        u32x4 u0 = s[0], u1 = s[1];
        *(u32x4*)(KT + row * 128 + ((q4 * 32) ^ sw)) = u0;
        *(u32x4*)(KT + row * 128 + ((q4 * 32 + 16) ^ sw)) = u1;
    }
    // prefetch q/vT chunk 0 (row = t>>2 serves both: q m-row and vT c-row)
    u32x4 qpf0, qpf1, vpf0, vpf1;
    {
        const u32x4* qs = (const u32x4*)(qg + (size_t)(b * 4096 + mbase + row) * 64 + q4 * 16);
        qpf0 = qs[0]; qpf1 = qs[1];
        const unsigned short* vs = vtg + (size_t)b * 262144 + row * 4096 + mbase + q4 * 16;
        vpf0 = *(const u32x4*)(vs);
        vpf1 = *(const u32x4*)(vs + 8);
    }
    __syncthreads();

    int lane = t & 63, wid = t >> 6, g = lane >> 4, ln = lane & 15;
    int krow = wid * 16 + ln;
    short8 kb0 = *(const short8*)(KT + krow * 128 + ((16 * g) ^ ((krow & 7) << 4)));
    short8 kb1 = *(const short8*)(KT + krow * 128 + ((64 + 16 * g) ^ ((krow & 7) << 4)));

    f32x4 z = {0.f, 0.f, 0.f, 0.f};
    f32x4 oacc[4] = {z, z, z, z};
    char* pbase = PL + wid * 2048;
    int psw = (ln & 7) << 4;
    const float* rblk = rinv + b * 4096 + mbase;

    for (int mc = 0; mc < 16; ++mc) {
        {   // write staged q/vT chunk mc (both use row, q4, sw)
            *(u32x4*)(QT + row * 128 + ((q4 * 32) ^ sw)) = qpf0;
            *(u32x4*)(QT + row * 128 + ((q4 * 32 + 16) ^ sw)) = qpf1;
            *(u32x4*)(VT + row * 128 + ((q4 * 32) ^ sw)) = vpf0;
            *(u32x4*)(VT + row * 128 + ((q4 * 32 + 16) ^ sw)) = vpf1;
        }
        __syncthreads();
        if (mc < 15) {   // prefetch chunk mc+1
            int m1 = mbase + (mc + 1) * 64;
            const u32x4* qs = (const u32x4*)(qg + (size_t)(b * 4096 + m1 + row) * 64 + q4 * 16);
            qpf0 = qs[0]; qpf1 = qs[1];
            const unsigned short* vs = vtg + (size_t)b * 262144 + row * 4096 + m1 + q4 * 16;
            vpf0 = *(const u32x4*)(vs);
            vpf1 = *(const u32x4*)(vs + 8);
        }
        const float* rp = rblk + mc * 64;
        #pragma unroll
        for (int s = 0; s < 4; ++s) {
            int qrow = 16 * s + ln;
            int qsw = (qrow & 7) << 4;
            short8 as0 = *(const short8*)(QT + qrow * 128 + ((16 * g) ^ qsw));
            short8 as1 = *(const short8*)(QT + qrow * 128 + ((64 + 16 * g) ^ qsw));
            f32x4 e = {0.f, 0.f, 0.f, 0.f};
            e = MFMA(as0, kb0, e);   // e[m'=16s+4g+r][n = n0+wid*16+ln]
            e = MFMA(as1, kb1, e);
            f32x4 rv = *(const f32x4*)(rp + 16 * s + 4 * g);
            float p0 = __expf(e[0]) * rv[0];
            float p1 = __expf(e[1]) * rv[1];
            float p2 = __expf(e[2]) * rv[2];
            float p3 = __expf(e[3]) * rv[3];
            u32x2 pu = { pack2(p0, p1), pack2(p2, p3) };
            *(u32x2*)(pbase + ln * 128 + ((32 * s + 8 * g) ^ psw)) = pu;
        }
        // PV: A = p[n=ln][m 0..63], B = vT[c][m 0..63]
        short8 pa0 = *(const short8*)(pbase + ln * 128 + ((16 * g) ^ psw));
        short8 pa1 = *(const short8*)(pbase + ln * 128 + ((64 + 16 * g) ^ psw));
        #pragma unroll
        for (int fb = 0; fb < 4; ++fb) {
            int crow = fb * 16 + ln;
            int csw = (crow & 7) << 4;
            short8 vb0 = *(const short8*)(VT + crow * 128 + ((16 * g) ^ csw));
            short8 vb1 = *(const short8*)(VT + crow * 128 + ((64 + 16 * g) ^ csw));
            oacc[fb] = MFMA(pa0, vb0, oacc[fb]);
            oacc[fb] = MFMA(pa1, vb1, oacc[fb]);
        }
        __syncthreads();
    }

    float gm = gamma[0];
    int nrow = b * 4096 + n0 + wid * 16 + 4 * g;
    #pragma unroll
    for (int fb = 0; fb < 4; ++fb) {
        #pragma unroll
        for (int r = 0; r < 4; ++r) {
            int idx = (nrow + r) * 64 + fb * 16 + ln;
            unsafeAtomicAdd(outp + idx, gm * oacc[fb][r]);
        }
    }
}

extern "C" void kernel_launch(void* const* d_in, const int* in_sizes, int n_in,
                              void* d_out, int out_size, void* d_ws, size_t ws_size,
                              hipStream_t stream) {
    const float* x  = (const float*)d_in[0];
    const float* Wq = (const float*)d_in[1];
    const float* bq = (const float*)d_in[2];
    const float* Wk = (const float*)d_in[3];
    const float* bk = (const float*)d_in[4];
    const float* Wv = (const float*)d_in[5];
    const float* bv = (const float*)d_in[6];
    const float* gm = (const float*)d_in[7];
    char* ws = (char*)d_ws;
    float* outp = (float*)d_out;

    unsigned short* qg  = (unsigned short*)(ws + OFF_Q);
    unsigned short* kg  = (unsigned short*)(ws + OFF_K);
    unsigned short* vtg = (unsigned short*)(ws + OFF_VT);
    unsigned short* wt  = (unsigned short*)(ws + OFF_WT);
    float* sbuf         = (float*)(ws + OFF_S);
    float* rinv         = (float*)(ws + OFF_RINV);

    k0z<<<64, 256, 0, stream>>>(Wq, Wk, Wv, wt, sbuf);
    k1_proj<<<256, 256, 0, stream>>>(x, wt, bq, bk, bv, qg, kg, vtg);
    k2_rowsum<<<1024, 256, 0, stream>>>(qg, kg, sbuf);
    r2_init<<<1024, 256, 0, stream>>>(sbuf, rinv, x, outp);
    k3_out<<<1024, 256, 0, stream>>>(qg, kg, vtg, rinv, gm, outp);
}